// Round 1
// baseline (4178.624 us; speedup 1.0000x reference)
//
#include <hip/hip_runtime.h>
#include <math.h>

#define NN 100000
#define EE 3200000
#define INF 128
#define OUTF 64
#define ALPHA 0.1f

// ---------------- GEMM: support0 = x @ W  ([N,128]@[128,64]) ----------------
__global__ __launch_bounds__(256) void gemm_kernel(
    const float* __restrict__ x, const float* __restrict__ W, float* __restrict__ out)
{
    __shared__ float Wl[INF * OUTF];  // 32 KB
    for (int idx = threadIdx.x; idx < INF * OUTF; idx += 256) Wl[idx] = W[idx];
    __syncthreads();

    int row = blockIdx.x * 4 + (threadIdx.x >> 6);
    int f = threadIdx.x & 63;
    if (row >= NN) return;
    const float* xr = x + (size_t)row * INF;
    float acc = 0.f;
#pragma unroll
    for (int k = 0; k < INF; k += 4) {
        float4 xv = *reinterpret_cast<const float4*>(xr + k);
        acc += xv.x * Wl[(k + 0) * OUTF + f];
        acc += xv.y * Wl[(k + 1) * OUTF + f];
        acc += xv.z * Wl[(k + 2) * OUTF + f];
        acc += xv.w * Wl[(k + 3) * OUTF + f];
    }
    out[(size_t)row * OUTF + f] = acc;
}

// ---------------- SpMM: Y += scatter(rows) of vals * X[cols]  (atomic) ------
__global__ __launch_bounds__(256) void spmm_atomic(
    const int* __restrict__ rows, const int* __restrict__ cols,
    const float* __restrict__ vals,
    const float* __restrict__ X, float* __restrict__ Y, int nedges)
{
    int lane = threadIdx.x & 63;
    int wave = (blockIdx.x << 2) + (threadIdx.x >> 6);
    int nwaves = gridDim.x << 2;
    for (int e = wave; e < nedges; e += nwaves) {
        int r = rows[e];
        int c = cols[e];
        float v = vals[e];
        float xv = X[(size_t)c * OUTF + lane];
        atomicAdd(&Y[(size_t)r * OUTF + lane], v * xv);
    }
}

// ---------------- Fused attention epilogue ----------------------------------
// per node i (one wave, lane = feature f):
//   att[i,k] = 1/6 for i<N/2, else softmax_k(leakyrelu(a_lo . ch_k[m] + a_hi . ch_k[m+1])),
//   m = 2i - N.  channels 3..5 take fabs.
//   h_prime[i,f] = (1/6) sum_j att[j] * ch_{(j*64+f)%6}[i, (j*64+f)/6]
__global__ __launch_bounds__(256) void fuse_kernel(
    const float* __restrict__ hA, const float* __restrict__ hA2, const float* __restrict__ hA3,
    const float* __restrict__ s1, const float* __restrict__ s2, const float* __restrict__ s3,
    const float* __restrict__ a, float* __restrict__ out)
{
    __shared__ float chl[4][6][OUTF];  // 6 KB
    int wid = threadIdx.x >> 6;
    int lane = threadIdx.x & 63;
    int i = blockIdx.x * 4 + wid;
    if (i >= NN) return;

    const float* bufs[6] = {hA, hA2, hA3, s1, s2, s3};

    // own-row channel values (abs on scatter channels)
#pragma unroll
    for (int k = 0; k < 6; k++) {
        float v = bufs[k][(size_t)i * OUTF + lane];
        if (k >= 3) v = fabsf(v);
        chl[wid][k][lane] = v;
    }

    float att[6];
    if (i < NN / 2) {
#pragma unroll
        for (int k = 0; k < 6; k++) att[k] = 1.0f / 6.0f;
    } else {
        int m = 2 * i - NN;
        float alo = a[lane];
        float ahi = a[64 + lane];
        float e[6];
#pragma unroll
        for (int k = 0; k < 6; k++) {
            float v0 = bufs[k][(size_t)m * OUTF + lane];
            float v1 = bufs[k][(size_t)(m + 1) * OUTF + lane];
            if (k >= 3) { v0 = fabsf(v0); v1 = fabsf(v1); }
            float p = alo * v0 + ahi * v1;
#pragma unroll
            for (int off = 32; off; off >>= 1) p += __shfl_xor(p, off);
            e[k] = (p > 0.f) ? p : ALPHA * p;
        }
        float mx = e[0];
#pragma unroll
        for (int k = 1; k < 6; k++) mx = fmaxf(mx, e[k]);
        float s = 0.f;
#pragma unroll
        for (int k = 0; k < 6; k++) { att[k] = __expf(e[k] - mx); s += att[k]; }
        float inv = 1.f / s;
#pragma unroll
        for (int k = 0; k < 6; k++) att[k] *= inv;
    }

    // attention output: [N,6,1] at offset N*OUTF
    if (lane < 6) out[(size_t)NN * OUTF + (size_t)i * 6 + lane] = att[lane];

    // h_prime with the permuted channel view (LDS written by this same wave)
    float hp = 0.f;
#pragma unroll
    for (int j = 0; j < 6; j++) {
        int g = j * 64 + lane;
        hp += att[j] * chl[wid][g % 6][g / 6];
    }
    out[(size_t)i * OUTF + lane] = hp * (1.0f / 6.0f);
}

extern "C" void kernel_launch(void* const* d_in, const int* in_sizes, int n_in,
                              void* d_out, int out_size, void* d_ws, size_t ws_size,
                              hipStream_t stream)
{
    const float* x = (const float*)d_in[0];
    const float* W = (const float*)d_in[1];
    const float* a = (const float*)d_in[2];
    const int*   A_rows = (const int*)d_in[3];
    const int*   A_cols = (const int*)d_in[4];
    const float* A_vals = (const float*)d_in[5];
    const int*   P1_rows = (const int*)d_in[6];
    const int*   P1_cols = (const int*)d_in[7];
    const float* P1_vals = (const float*)d_in[8];
    const int*   P2_rows = (const int*)d_in[9];
    const int*   P2_cols = (const int*)d_in[10];
    const float* P2_vals = (const float*)d_in[11];
    const int*   P3_rows = (const int*)d_in[12];
    const int*   P3_cols = (const int*)d_in[13];
    const float* P3_vals = (const float*)d_in[14];

    const size_t NF = (size_t)NN * OUTF;  // 6.4M floats
    float* ws = (float*)d_ws;
    float* support0 = ws;
    float* hA  = ws + NF * 1;
    float* hA2 = ws + NF * 2;
    float* hA3 = ws + NF * 3;
    float* s1  = ws + NF * 4;
    float* s2  = ws + NF * 5;
    float* s3  = ws + NF * 6;

    // zero the 6 atomic-accumulation buffers (every call; harness doesn't re-zero ws)
    hipMemsetAsync(hA, 0, NF * 6 * sizeof(float), stream);

    gemm_kernel<<<NN / 4, 256, 0, stream>>>(x, W, support0);

    const int SPMM_BLOCKS = 4096;
    spmm_atomic<<<SPMM_BLOCKS, 256, 0, stream>>>(A_rows, A_cols, A_vals, support0, hA, EE);
    spmm_atomic<<<SPMM_BLOCKS, 256, 0, stream>>>(A_rows, A_cols, A_vals, hA, hA2, EE);
    spmm_atomic<<<SPMM_BLOCKS, 256, 0, stream>>>(A_rows, A_cols, A_vals, hA2, hA3, EE);
    spmm_atomic<<<SPMM_BLOCKS, 256, 0, stream>>>(P1_rows, P1_cols, P1_vals, support0, s1, EE);
    spmm_atomic<<<SPMM_BLOCKS, 256, 0, stream>>>(P2_rows, P2_cols, P2_vals, support0, s2, EE);
    spmm_atomic<<<SPMM_BLOCKS, 256, 0, stream>>>(P3_rows, P3_cols, P3_vals, support0, s3, EE);

    fuse_kernel<<<(NN + 3) / 4, 256, 0, stream>>>(hA, hA2, hA3, s1, s2, s3, a, (float*)d_out);
}

// Round 3
// 2374.172 us; speedup vs baseline: 1.7600x; 1.7600x over previous
//
#include <hip/hip_runtime.h>
#include <math.h>

#define NN 100000
#define EE 3200000
#define INF 128
#define OUTF 64
#define ALPHA 0.1f
#define NPR ((NN + 1023) / 1024)   // 98 scan partials

// ---------------- GEMM: support0 = x @ W  ([N,128]@[128,64]) ----------------
__global__ __launch_bounds__(256) void gemm_kernel(
    const float* __restrict__ x, const float* __restrict__ W, float* __restrict__ out)
{
    __shared__ float Wl[INF * OUTF];  // 32 KB
    for (int idx = threadIdx.x; idx < INF * OUTF; idx += 256) Wl[idx] = W[idx];
    __syncthreads();

    int row = blockIdx.x * 4 + (threadIdx.x >> 6);
    int f = threadIdx.x & 63;
    if (row >= NN) return;
    const float* xr = x + (size_t)row * INF;
    float acc = 0.f;
#pragma unroll
    for (int k = 0; k < INF; k += 4) {
        float4 xv = *reinterpret_cast<const float4*>(xr + k);
        acc += xv.x * Wl[(k + 0) * OUTF + f];
        acc += xv.y * Wl[(k + 1) * OUTF + f];
        acc += xv.z * Wl[(k + 2) * OUTF + f];
        acc += xv.w * Wl[(k + 3) * OUTF + f];
    }
    out[(size_t)row * OUTF + f] = acc;
}

// ---------------- CSR build: histogram -> scan -> scatter -------------------
__global__ __launch_bounds__(256) void hist_kernel(
    const int* __restrict__ rows, int* __restrict__ counts, int n)
{
    int i = blockIdx.x * 256 + threadIdx.x;
    if (i < n) atomicAdd(&counts[rows[i]], 1);
}

// per-block exclusive scan over 1024-int chunks; block totals -> partials
__global__ __launch_bounds__(256) void scan_block(
    const int* __restrict__ data, int* __restrict__ excl_out,
    int* __restrict__ partials, int n)
{
    __shared__ int lds[256];
    int t = threadIdx.x;
    int base = blockIdx.x * 1024 + t * 4;
    int v0 = (base + 0 < n) ? data[base + 0] : 0;
    int v1 = (base + 1 < n) ? data[base + 1] : 0;
    int v2 = (base + 2 < n) ? data[base + 2] : 0;
    int v3 = (base + 3 < n) ? data[base + 3] : 0;
    int s = v0 + v1 + v2 + v3;
    lds[t] = s;
    __syncthreads();
#pragma unroll
    for (int off = 1; off < 256; off <<= 1) {
        int w = (t >= off) ? lds[t - off] : 0;
        __syncthreads();
        lds[t] += w;
        __syncthreads();
    }
    int excl = lds[t] - s;
    if (base + 0 < n) excl_out[base + 0] = excl;
    if (base + 1 < n) excl_out[base + 1] = excl + v0;
    if (base + 2 < n) excl_out[base + 2] = excl + v0 + v1;
    if (base + 3 < n) excl_out[base + 3] = excl + v0 + v1 + v2;
    if (t == 255) partials[blockIdx.x] = lds[255];
}

__global__ __launch_bounds__(128) void scan_partials(int* __restrict__ partials, int n)
{
    __shared__ int lds[128];
    int t = threadIdx.x;
    int v = (t < n) ? partials[t] : 0;
    lds[t] = v;
    __syncthreads();
#pragma unroll
    for (int off = 1; off < 128; off <<= 1) {
        int w = (t >= off) ? lds[t - off] : 0;
        __syncthreads();
        lds[t] += w;
        __syncthreads();
    }
    if (t < n) partials[t] = lds[t] - v;   // exclusive, in place
}

__global__ __launch_bounds__(256) void scan_finish(
    const int* __restrict__ excl, const int* __restrict__ partials,
    int* __restrict__ rowptr, int* __restrict__ cursor, int n, int total)
{
    int i = blockIdx.x * 256 + threadIdx.x;
    if (i < n) {
        int p = excl[i] + partials[i >> 10];
        rowptr[i] = p;
        cursor[i] = p;
    }
    if (i == 0) rowptr[n] = total;
}

__global__ __launch_bounds__(256) void scatter_kernel(
    const int* __restrict__ rows, const int* __restrict__ cols,
    const float* __restrict__ vals, int* __restrict__ cursor,
    int2* __restrict__ perm, int n)
{
    int i = blockIdx.x * 256 + threadIdx.x;
    if (i < n) {
        int r = rows[i];
        int pos = atomicAdd(&cursor[r], 1);
        int2 p;
        p.x = cols[i];
        p.y = __float_as_int(vals[i]);
        perm[pos] = p;
    }
}

// ---------------- SpMM (CSR gather-reduce): one wave per row ----------------
__global__ __launch_bounds__(256) void spmm_csr(
    const int* __restrict__ rowptr, const int2* __restrict__ perm,
    const float* __restrict__ X, float* __restrict__ Y)
{
    int row = blockIdx.x * 4 + (threadIdx.x >> 6);
    int lane = threadIdx.x & 63;
    if (row >= NN) return;
    int s = rowptr[row];
    int e = rowptr[row + 1];
    float acc = 0.f;
    int i = s;
    for (; i + 3 < e; i += 4) {
        int2 p0 = perm[i + 0];
        int2 p1 = perm[i + 1];
        int2 p2 = perm[i + 2];
        int2 p3 = perm[i + 3];
        float x0 = X[(size_t)p0.x * OUTF + lane];
        float x1 = X[(size_t)p1.x * OUTF + lane];
        float x2 = X[(size_t)p2.x * OUTF + lane];
        float x3 = X[(size_t)p3.x * OUTF + lane];
        acc += __int_as_float(p0.y) * x0;
        acc += __int_as_float(p1.y) * x1;
        acc += __int_as_float(p2.y) * x2;
        acc += __int_as_float(p3.y) * x3;
    }
    for (; i < e; i++) {
        int2 p = perm[i];
        acc += __int_as_float(p.y) * X[(size_t)p.x * OUTF + lane];
    }
    Y[(size_t)row * OUTF + lane] = acc;
}

// ---------------- Fused attention epilogue ----------------------------------
__global__ __launch_bounds__(256) void fuse_kernel(
    const float* __restrict__ hA, const float* __restrict__ hA2, const float* __restrict__ hA3,
    const float* __restrict__ s1, const float* __restrict__ s2, const float* __restrict__ s3,
    const float* __restrict__ a, float* __restrict__ out)
{
    __shared__ float chl[4][6][OUTF];  // 6 KB
    int wid = threadIdx.x >> 6;
    int lane = threadIdx.x & 63;
    int i = blockIdx.x * 4 + wid;
    if (i >= NN) return;

    const float* bufs[6] = {hA, hA2, hA3, s1, s2, s3};

#pragma unroll
    for (int k = 0; k < 6; k++) {
        float v = bufs[k][(size_t)i * OUTF + lane];
        if (k >= 3) v = fabsf(v);
        chl[wid][k][lane] = v;
    }

    float att[6];
    if (i < NN / 2) {
#pragma unroll
        for (int k = 0; k < 6; k++) att[k] = 1.0f / 6.0f;
    } else {
        int m = 2 * i - NN;
        float alo = a[lane];
        float ahi = a[64 + lane];
        float e[6];
#pragma unroll
        for (int k = 0; k < 6; k++) {
            float v0 = bufs[k][(size_t)m * OUTF + lane];
            float v1 = bufs[k][(size_t)(m + 1) * OUTF + lane];
            if (k >= 3) { v0 = fabsf(v0); v1 = fabsf(v1); }
            float p = alo * v0 + ahi * v1;
#pragma unroll
            for (int off = 32; off; off >>= 1) p += __shfl_xor(p, off);
            e[k] = (p > 0.f) ? p : ALPHA * p;
        }
        float mx = e[0];
#pragma unroll
        for (int k = 1; k < 6; k++) mx = fmaxf(mx, e[k]);
        float s = 0.f;
#pragma unroll
        for (int k = 0; k < 6; k++) { att[k] = __expf(e[k] - mx); s += att[k]; }
        float inv = 1.f / s;
#pragma unroll
        for (int k = 0; k < 6; k++) att[k] *= inv;
    }

    if (lane < 6) out[(size_t)NN * OUTF + (size_t)i * 6 + lane] = att[lane];

    float hp = 0.f;
#pragma unroll
    for (int j = 0; j < 6; j++) {
        int g = j * 64 + lane;
        hp += att[j] * chl[wid][g % 6][g / 6];
    }
    out[(size_t)i * OUTF + lane] = hp * (1.0f / 6.0f);
}

extern "C" void kernel_launch(void* const* d_in, const int* in_sizes, int n_in,
                              void* d_out, int out_size, void* d_ws, size_t ws_size,
                              hipStream_t stream)
{
    const float* x = (const float*)d_in[0];
    const float* W = (const float*)d_in[1];
    const float* a = (const float*)d_in[2];
    const int*   A_rows  = (const int*)d_in[3];
    const int*   A_cols  = (const int*)d_in[4];
    const float* A_vals  = (const float*)d_in[5];
    const int*   P1_rows = (const int*)d_in[6];
    const int*   P1_cols = (const int*)d_in[7];
    const float* P1_vals = (const float*)d_in[8];
    const int*   P2_rows = (const int*)d_in[9];
    const int*   P2_cols = (const int*)d_in[10];
    const float* P2_vals = (const float*)d_in[11];
    const int*   P3_rows = (const int*)d_in[12];
    const int*   P3_cols = (const int*)d_in[13];
    const float* P3_vals = (const float*)d_in[14];

    const size_t NF = (size_t)NN * OUTF;  // 6.4M floats

    // ---- workspace: 6 dense slots + 1 shared perm = exactly 179.2 MB ----
    float* ws = (float*)d_ws;
    float* S0 = ws + NF * 0;   // support0, later hA2
    float* S1 = ws + NF * 1;   // s1
    float* S2 = ws + NF * 2;   // s2
    float* S3 = ws + NF * 3;   // s3
    float* S4 = ws + NF * 4;   // hA
    float* S5 = ws + NF * 5;   // hA3
    int2* perm = (int2*)(ws + NF * 6);   // 3.2M edges, 25.6 MB, rebuilt per matrix

    // ---- CSR metadata lives in d_out (scratch until fuse overwrites it) ----
    int* meta = (int*)d_out;             // 3*NN+1+NPR ints = 1.2 MB << 28 MB
    int* counts   = meta;                // NN
    int* rowptr   = meta + NN;           // NN+1
    int* cursor   = meta + 2 * NN + 1;   // NN
    int* partials = meta + 3 * NN + 1;   // NPR

    const int EB = (EE + 255) / 256;     // 12500
    const int RB = (NN + 3) / 4;         // 25000

    auto build = [&](const int* rows, const int* cols, const float* vals) {
        hipMemsetAsync(counts, 0, (size_t)NN * sizeof(int), stream);
        hist_kernel<<<EB, 256, 0, stream>>>(rows, counts, EE);
        scan_block<<<NPR, 256, 0, stream>>>(counts, counts, partials, NN);
        scan_partials<<<1, 128, 0, stream>>>(partials, NPR);
        scan_finish<<<(NN + 255) / 256, 256, 0, stream>>>(counts, partials, rowptr, cursor, NN, EE);
        scatter_kernel<<<EB, 256, 0, stream>>>(rows, cols, vals, cursor, perm, EE);
    };

    gemm_kernel<<<NN / 4, 256, 0, stream>>>(x, W, S0);

    build(P1_rows, P1_cols, P1_vals);
    spmm_csr<<<RB, 256, 0, stream>>>(rowptr, perm, S0, S1);          // s1
    build(P2_rows, P2_cols, P2_vals);
    spmm_csr<<<RB, 256, 0, stream>>>(rowptr, perm, S0, S2);          // s2
    build(P3_rows, P3_cols, P3_vals);
    spmm_csr<<<RB, 256, 0, stream>>>(rowptr, perm, S0, S3);          // s3
    build(A_rows, A_cols, A_vals);
    spmm_csr<<<RB, 256, 0, stream>>>(rowptr, perm, S0, S4);          // hA   (support0 dead now)
    spmm_csr<<<RB, 256, 0, stream>>>(rowptr, perm, S4, S0);          // hA2  (reuses S0)
    spmm_csr<<<RB, 256, 0, stream>>>(rowptr, perm, S0, S5);          // hA3

    fuse_kernel<<<RB, 256, 0, stream>>>(S4, S0, S5, S1, S2, S3, a, (float*)d_out);
}